// Round 6
// baseline (229.434 us; speedup 1.0000x reference)
//
#include <hip/hip_runtime.h>

#define NROWS 8192
#define KDIM  256
#define NT    64                  // NROWS / 128
#define NBLK  (NT * (NT + 1) / 2) // 2080 upper-triangular 128x128 tiles
#define GRID  256                 // persistent blocks; strided walk (L2 band)

typedef __attribute__((ext_vector_type(4)))  float f32x4;
typedef __attribute__((ext_vector_type(16))) float f32x16;
typedef __attribute__((ext_vector_type(4)))  int   i32x4;
typedef __attribute__((ext_vector_type(8)))  int   i32x8;

// async global->LDS, 16B per lane; LDS dest is wave-uniform base + lane*16
#define GLD(gp, lp)                                                            \
  __builtin_amdgcn_global_load_lds(                                            \
      (const __attribute__((address_space(1))) void*)(gp),                     \
      (__attribute__((address_space(3))) void*)(lp), 16, 0, 0)

// ---------------------------------------------------------------------------
// Kernel 1: fp32 -> fp8 e4m3 (OCP) convert + per-row meta {sumsq/256, label}.
// 256 blocks x 256 threads, one wave per row (grid-stride, 8 rows/wave).
// Also zeroes out[0] (pair_kernel atomics accumulate the final scalar there).
// ---------------------------------------------------------------------------
__global__ __launch_bounds__(256) void prep_kernel(
    const float* __restrict__ samples, const int* __restrict__ labels,
    unsigned char* __restrict__ sf8, float2* __restrict__ meta,
    float* __restrict__ out) {
  int tid = blockIdx.x * 256 + threadIdx.x;
  int gw = tid >> 6;        // global wave id, 0..1023
  int lane = tid & 63;
#pragma unroll
  for (int it = 0; it < NROWS / 1024; ++it) {
    int row = gw + it * 1024;
    f32x4 v = ((const f32x4*)samples)[(size_t)row * 64 + lane];
    int pk = __builtin_amdgcn_cvt_pk_fp8_f32(v.x, v.y, 0, false);
    pk = __builtin_amdgcn_cvt_pk_fp8_f32(v.z, v.w, pk, true);
    ((unsigned int*)sf8)[(size_t)row * 64 + lane] = (unsigned int)pk;
    float p = v.x * v.x + v.y * v.y + v.z * v.z + v.w * v.w;
#pragma unroll
    for (int off = 32; off; off >>= 1) p += __shfl_down(p, off);
    if (lane == 0)
      meta[row] = make_float2(p * (1.0f / 256.0f), (float)labels[row]);
  }
  if (tid == 0) out[0] = 0.0f;
}

// decode triangular index b -> (bi, bj), bi <= bj  (verified over 0..NBLK-1)
__device__ inline void decode_tile(int b, int& bi, int& bj) {
  float disc = (2.0f * NT + 1.0f) * (2.0f * NT + 1.0f) - 8.0f * (float)b;
  bi = (int)(((2.0f * NT + 1.0f) - sqrtf(disc)) * 0.5f);
  if (bi < 0) bi = 0;
  if (bi > NT - 1) bi = NT - 1;
  while (bi > 0 && (bi * NT - bi * (bi - 1) / 2) > b) --bi;
  while (((bi + 1) * NT - (bi + 1) * bi / 2) <= b) ++bi;
  bj = bi + (b - (bi * NT - bi * (bi - 1) / 2));
}

// ---------------------------------------------------------------------------
// Kernel 2: persistent blocks, STRIDED tile walk (tile += GRID: all blocks
// work one contiguous 256-tile band -> each A panel shared by ~32 blocks in
// L2; R4 proved chunked walks break this). Tile-level double-buffered fp8
// panels, XOR-16B swizzle on the GLOBAL side of global_load_lds.
//
// R5 counters showed the 512-thread version latency-bound: MfmaUtil 6.4%,
// VALUBusy 21.7%, Occupancy 18.3%, ~8.5k stall cy/tile with only 2 waves/SIMD.
// => 1024 threads = 16 waves = 4 waves/SIMD, each wave a 32x32 quadrant:
// per-wave serial work halves (4 dependent MFMA, 12 ds_reads, 16-out epi)
// and 4 waves interleave to hide ds_read/MFMA/GLD latency. LDS unchanged
// (128.5 KB, 1 block/CU); __launch_bounds__(1024,4) caps VGPR at 128.
// Deferred epilogue (T15): two acc banks ping-pong; tile t's epilogue VALU
// runs inside tile t+1's MFMA phase. One barrier per tile; prefetch flies a
// full tile ahead. One scaled atomic into out[0] per block.
// ---------------------------------------------------------------------------
__global__ __launch_bounds__(1024, 4) void pair_kernel(
    const unsigned char* __restrict__ sf8, const float2* __restrict__ meta,
    float* __restrict__ out) {

  __shared__ __align__(16) unsigned char As[2][128 * 256];
  __shared__ __align__(16) unsigned char Bs[2][128 * 256];
  __shared__ float red[16];

  int t = threadIdx.x;
  int lane = t & 63;
  int w = t >> 6;               // 0..15
  int wm = w >> 2, wn = w & 3;  // 4x4 wave grid: rows wm*32+, cols wn*32+
  int lr = lane >> 4, pc = lane & 15;  // staging: row-in-region, phys chunk
  int l31 = lane & 31;                 // fragment row/col within 32
  int hk  = lane >> 5;                 // k-half selector (0/1)

  float stt = 0.f;

  // stage tile (bi,bj): 32 regions x 1KB per matrix, wave w owns regions
  // {w, 16+w}; XOR-16B swizzle applied on the GLOBAL side
  auto stage = [&](int bi_, int bj_, int buf) {
    int rA = bi_ * 128, rB = bj_ * 128;
#pragma unroll
    for (int p = 0; p < 2; ++p) {
      int region = p * 16 + w;
      int rr = region * 4 + lr;
      int c = pc ^ (rr & 15);
      GLD(sf8 + (size_t)(rA + rr) * KDIM + c * 16, &As[buf][region * 1024]);
      GLD(sf8 + (size_t)(rB + rr) * KDIM + c * 16, &Bs[buf][region * 1024]);
    }
  };

  int tile = blockIdx.x;
  int bi, bj;
  decode_tile(tile, bi, bj);
  stage(bi, bj, 0);
  int cur = 0;

  // deferred-epilogue state (scalars reloaded per iter; meta is L2-resident)
  int pbi = 0, pbj = 0;
  float sqa[16], laa[16], sqbv = 0.f, labv = 0.f, pwt = 1.f;
  f32x16 accA, accB;

  // per-row scalars for the deferred tile; issued BEFORE prefetch GLDs so
  // their (in-order) vmcnt waits don't force prefetch completion.
  // C/D layout (32x32): col = lane&31, row = (reg&3)+8*(reg>>2)+4*(lane>>5)
  auto load_scalars = [&](int pbi_, int pbj_) {
#pragma unroll
    for (int g = 0; g < 4; ++g) {
      int gr = pbi_ * 128 + wm * 32 + g * 8 + 4 * hk;  // rows gr..gr+3
      f32x4 m0 = *(const f32x4*)(meta + gr);
      f32x4 m1 = *(const f32x4*)(meta + gr + 2);
      sqa[g * 4 + 0] = m0.x; laa[g * 4 + 0] = m0.y;
      sqa[g * 4 + 1] = m0.z; laa[g * 4 + 1] = m0.w;
      sqa[g * 4 + 2] = m1.x; laa[g * 4 + 2] = m1.y;
      sqa[g * 4 + 3] = m1.z; laa[g * 4 + 3] = m1.w;
    }
    float2 mb = meta[pbj_ * 128 + wn * 32 + l31];
    sqbv = mb.x; labv = mb.y;
    pwt = (pbi_ == pbj_) ? 1.0f : 2.0f;
  };

  // MFMA phase on buf[cur]: 4x mfma_scale 32x32x64 fp8 (e8m0 127 = 1.0)
  auto domfma = [&](f32x16& acc) {
#pragma unroll
    for (int e = 0; e < 16; ++e) acc[e] = 0.f;
    int m = wm * 32 + l31, n = wn * 32 + l31;
    const unsigned char* ab = &As[cur][m * 256];
    const unsigned char* bb = &Bs[cur][n * 256];
    int sm = m & 15, sn = n & 15;
#pragma unroll
    for (int kt = 0; kt < 4; ++kt) {
      int c0 = kt * 4 + hk * 2;  // logical 16B-chunk pair for this lane
      i32x4 alo = *(const i32x4*)(ab + ((c0 ^ sm) << 4));
      i32x4 ahi = *(const i32x4*)(ab + (((c0 + 1) ^ sm) << 4));
      i32x8 av = {alo.x, alo.y, alo.z, alo.w, ahi.x, ahi.y, ahi.z, ahi.w};
      i32x4 blo = *(const i32x4*)(bb + ((c0 ^ sn) << 4));
      i32x4 bhi = *(const i32x4*)(bb + (((c0 + 1) ^ sn) << 4));
      i32x8 bv = {blo.x, blo.y, blo.z, blo.w, bhi.x, bhi.y, bhi.z, bhi.w};
      acc = __builtin_amdgcn_mfma_scale_f32_32x32x64_f8f6f4(
          av, bv, acc, 0, 0, 0, 127, 0, 127);
    }
  };

  // epilogue for the deferred tile: gram -> S -> hinge/same, one accumulator
  auto epi = [&](const f32x16& acc) {
    float s = 0.f;
#pragma unroll
    for (int g2 = 0; g2 < 16; ++g2) {
      float S = sqa[g2] + sqbv - acc[g2] * (1.0f / 128.0f);
      float h = fmaxf(0.f, 1.f - S);
      s += (laa[g2] == labv) ? S : h;
    }
    stt += pwt * s;
  };

  int k = 0;
  while (tile < NBLK) {
    int ntile = tile + GRID;
    int nbi = 0, nbj = 0;
    bool have_next = ntile < NBLK;
    if (have_next) decode_tile(ntile, nbi, nbj);

    __syncthreads();  // buf[cur] staging complete (vmcnt drain at barrier)

    bool have_prev = (k > 0);
    if (have_prev) load_scalars(pbi, pbj);  // L2-hit loads, consumed in epi

    if (have_next) stage(nbi, nbj, cur ^ 1);  // async prefetch, other buffer

    // MFMA(cur tile) interleaved (separate pipes) with epilogue(prev tile)
    if (k & 1) {
      domfma(accB);
      if (have_prev) epi(accA);
    } else {
      domfma(accA);
      if (have_prev) epi(accB);
    }

    pbi = bi; pbj = bj;
    tile = ntile; bi = nbi; bj = nbj; cur ^= 1; ++k;
  }

  // drain: epilogue for the last computed tile (bank = parity of k-1)
  load_scalars(pbi, pbj);
  if ((k - 1) & 1) epi(accB);
  else             epi(accA);

  // ---- once per block: reduce 16 waves, 1 scaled atomic into out[0] ----
#pragma unroll
  for (int off = 32; off; off >>= 1) stt += __shfl_down(stt, off);
  if (lane == 0) red[w] = stt;
  __syncthreads();
  if (t == 0) {
    float a = 0.f;
#pragma unroll
    for (int q = 0; q < 16; q++) a += red[q];
    atomicAdd(&out[0], a * (10.0f / ((float)NROWS * (float)NROWS)));
  }
}

extern "C" void kernel_launch(void* const* d_in, const int* in_sizes, int n_in,
                              void* d_out, int out_size, void* d_ws,
                              size_t ws_size, hipStream_t stream) {
  // inputs: 0=merged (unused), 1=input1 (unused), 2=samples, 3=labels
  const float* samples = (const float*)d_in[2];
  const int*   labels  = (const int*)d_in[3];

  char* ws = (char*)d_ws;
  unsigned char* sf8 = (unsigned char*)ws;                  // 2 MiB fp8
  float2* meta = (float2*)(ws + (size_t)NROWS * KDIM);      // 64 KiB
  float* out   = (float*)d_out;

  prep_kernel<<<GRID, 256, 0, stream>>>(samples, labels, sf8, meta, out);
  pair_kernel<<<GRID, 1024, 0, stream>>>(sf8, meta, out);
}

// Round 7
// 226.983 us; speedup vs baseline: 1.0108x; 1.0108x over previous
//
#include <hip/hip_runtime.h>

#define NROWS 8192
#define KDIM  256
#define NT    64                  // NROWS / 128
#define NBLK  (NT * (NT + 1) / 2) // 2080 upper-triangular 128x128 tiles
#define GRID  256                 // persistent blocks; strided walk (L2 band)

typedef __attribute__((ext_vector_type(4)))  float f32x4;
typedef __attribute__((ext_vector_type(16))) float f32x16;
typedef __attribute__((ext_vector_type(4)))  int   i32x4;
typedef __attribute__((ext_vector_type(8)))  int   i32x8;

// async global->LDS, 16B per lane; LDS dest is wave-uniform base + lane*16
#define GLD(gp, lp)                                                            \
  __builtin_amdgcn_global_load_lds(                                            \
      (const __attribute__((address_space(1))) void*)(gp),                     \
      (__attribute__((address_space(3))) void*)(lp), 16, 0, 0)

// ---------------------------------------------------------------------------
// Kernel 1: fp32 -> fp8 e4m3 (OCP) convert + per-row meta {sumsq/256, label}.
// 256 blocks x 256 threads, one wave per row (grid-stride, 8 rows/wave).
// Also zeroes out[0] (pair_kernel atomics accumulate the final scalar there).
// ---------------------------------------------------------------------------
__global__ __launch_bounds__(256) void prep_kernel(
    const float* __restrict__ samples, const int* __restrict__ labels,
    unsigned char* __restrict__ sf8, float2* __restrict__ meta,
    float* __restrict__ out) {
  int tid = blockIdx.x * 256 + threadIdx.x;
  int gw = tid >> 6;        // global wave id, 0..1023
  int lane = tid & 63;
#pragma unroll
  for (int it = 0; it < NROWS / 1024; ++it) {
    int row = gw + it * 1024;
    f32x4 v = ((const f32x4*)samples)[(size_t)row * 64 + lane];
    int pk = __builtin_amdgcn_cvt_pk_fp8_f32(v.x, v.y, 0, false);
    pk = __builtin_amdgcn_cvt_pk_fp8_f32(v.z, v.w, pk, true);
    ((unsigned int*)sf8)[(size_t)row * 64 + lane] = (unsigned int)pk;
    float p = v.x * v.x + v.y * v.y + v.z * v.z + v.w * v.w;
#pragma unroll
    for (int off = 32; off; off >>= 1) p += __shfl_down(p, off);
    if (lane == 0)
      meta[row] = make_float2(p * (1.0f / 256.0f), (float)labels[row]);
  }
  if (tid == 0) out[0] = 0.0f;
}

// decode triangular index b -> (bi, bj), bi <= bj  (verified over 0..NBLK-1)
__device__ inline void decode_tile(int b, int& bi, int& bj) {
  float disc = (2.0f * NT + 1.0f) * (2.0f * NT + 1.0f) - 8.0f * (float)b;
  bi = (int)(((2.0f * NT + 1.0f) - sqrtf(disc)) * 0.5f);
  if (bi < 0) bi = 0;
  if (bi > NT - 1) bi = NT - 1;
  while (bi > 0 && (bi * NT - bi * (bi - 1) / 2) > b) --bi;
  while (((bi + 1) * NT - (bi + 1) * bi / 2) <= b) ++bi;
  bj = bi + (b - (bi * NT - bi * (bi - 1) / 2));
}

// ---------------------------------------------------------------------------
// Kernel 2: persistent blocks, STRIDED tile walk (tile += GRID: all blocks
// work one contiguous 256-tile band -> each A panel shared by ~32 blocks in
// L2; R4 proved chunked walks break this). Tile-level double-buffered fp8
// panels, XOR-16B swizzle on the GLOBAL side of global_load_lds.
//
// 1024 threads = 16 waves = 4 waves/SIMD (R5 showed 2 waves/SIMD is
// latency-bound: MfmaUtil 6.4%), each wave a 32x32 quadrant.
// REGISTER CAP LESSON (R6): __launch_bounds__(1024,4) made the compiler cap
// VGPRs at 64 -> the ~110-reg working set spilled to scratch -> 429 MB of
// HBM spill traffic, 129 us. Plain __launch_bounds__(1024) caps at 128
// (2048-reg pool / 16 waves), which fits without spilling; LDS (128.5 KB)
// already limits to 1 block/CU so a tighter cap buys nothing.
// Deferred epilogue (T15): two acc banks ping-pong; tile t's epilogue VALU
// runs inside tile t+1's MFMA phase. One barrier per tile; prefetch flies a
// full tile ahead. One scaled atomic into out[0] per block.
// ---------------------------------------------------------------------------
__global__ __launch_bounds__(1024) void pair_kernel(
    const unsigned char* __restrict__ sf8, const float2* __restrict__ meta,
    float* __restrict__ out) {

  __shared__ __align__(16) unsigned char As[2][128 * 256];
  __shared__ __align__(16) unsigned char Bs[2][128 * 256];
  __shared__ float red[16];

  int t = threadIdx.x;
  int lane = t & 63;
  int w = t >> 6;               // 0..15
  int wm = w >> 2, wn = w & 3;  // 4x4 wave grid: rows wm*32+, cols wn*32+
  int lr = lane >> 4, pc = lane & 15;  // staging: row-in-region, phys chunk
  int l31 = lane & 31;                 // fragment row/col within 32
  int hk  = lane >> 5;                 // k-half selector (0/1)

  float stt = 0.f;

  // stage tile (bi,bj): 32 regions x 1KB per matrix, wave w owns regions
  // {w, 16+w}; XOR-16B swizzle applied on the GLOBAL side
  auto stage = [&](int bi_, int bj_, int buf) {
    int rA = bi_ * 128, rB = bj_ * 128;
#pragma unroll
    for (int p = 0; p < 2; ++p) {
      int region = p * 16 + w;
      int rr = region * 4 + lr;
      int c = pc ^ (rr & 15);
      GLD(sf8 + (size_t)(rA + rr) * KDIM + c * 16, &As[buf][region * 1024]);
      GLD(sf8 + (size_t)(rB + rr) * KDIM + c * 16, &Bs[buf][region * 1024]);
    }
  };

  int tile = blockIdx.x;
  int bi, bj;
  decode_tile(tile, bi, bj);
  stage(bi, bj, 0);
  int cur = 0;

  // deferred-epilogue state (scalars reloaded per iter; meta is L2-resident)
  int pbi = 0, pbj = 0;
  float sqa[16], laa[16], sqbv = 0.f, labv = 0.f, pwt = 1.f;
  f32x16 accA, accB;

  // per-row scalars for the deferred tile; issued BEFORE prefetch GLDs so
  // their (in-order) vmcnt waits don't force prefetch completion.
  // C/D layout (32x32): col = lane&31, row = (reg&3)+8*(reg>>2)+4*(lane>>5)
  auto load_scalars = [&](int pbi_, int pbj_) {
#pragma unroll
    for (int g = 0; g < 4; ++g) {
      int gr = pbi_ * 128 + wm * 32 + g * 8 + 4 * hk;  // rows gr..gr+3
      f32x4 m0 = *(const f32x4*)(meta + gr);
      f32x4 m1 = *(const f32x4*)(meta + gr + 2);
      sqa[g * 4 + 0] = m0.x; laa[g * 4 + 0] = m0.y;
      sqa[g * 4 + 1] = m0.z; laa[g * 4 + 1] = m0.w;
      sqa[g * 4 + 2] = m1.x; laa[g * 4 + 2] = m1.y;
      sqa[g * 4 + 3] = m1.z; laa[g * 4 + 3] = m1.w;
    }
    float2 mb = meta[pbj_ * 128 + wn * 32 + l31];
    sqbv = mb.x; labv = mb.y;
    pwt = (pbi_ == pbj_) ? 1.0f : 2.0f;
  };

  // MFMA phase on buf[cur]: 4x mfma_scale 32x32x64 fp8 (e8m0 127 = 1.0)
  auto domfma = [&](f32x16& acc) {
#pragma unroll
    for (int e = 0; e < 16; ++e) acc[e] = 0.f;
    int m = wm * 32 + l31, n = wn * 32 + l31;
    const unsigned char* ab = &As[cur][m * 256];
    const unsigned char* bb = &Bs[cur][n * 256];
    int sm = m & 15, sn = n & 15;
#pragma unroll
    for (int kt = 0; kt < 4; ++kt) {
      int c0 = kt * 4 + hk * 2;  // logical 16B-chunk pair for this lane
      i32x4 alo = *(const i32x4*)(ab + ((c0 ^ sm) << 4));
      i32x4 ahi = *(const i32x4*)(ab + (((c0 + 1) ^ sm) << 4));
      i32x8 av = {alo.x, alo.y, alo.z, alo.w, ahi.x, ahi.y, ahi.z, ahi.w};
      i32x4 blo = *(const i32x4*)(bb + ((c0 ^ sn) << 4));
      i32x4 bhi = *(const i32x4*)(bb + (((c0 + 1) ^ sn) << 4));
      i32x8 bv = {blo.x, blo.y, blo.z, blo.w, bhi.x, bhi.y, bhi.z, bhi.w};
      acc = __builtin_amdgcn_mfma_scale_f32_32x32x64_f8f6f4(
          av, bv, acc, 0, 0, 0, 127, 0, 127);
    }
  };

  // epilogue for the deferred tile: gram -> S -> hinge/same, one accumulator
  auto epi = [&](const f32x16& acc) {
    float s = 0.f;
#pragma unroll
    for (int g2 = 0; g2 < 16; ++g2) {
      float S = sqa[g2] + sqbv - acc[g2] * (1.0f / 128.0f);
      float h = fmaxf(0.f, 1.f - S);
      s += (laa[g2] == labv) ? S : h;
    }
    stt += pwt * s;
  };

  int k = 0;
  while (tile < NBLK) {
    int ntile = tile + GRID;
    int nbi = 0, nbj = 0;
    bool have_next = ntile < NBLK;
    if (have_next) decode_tile(ntile, nbi, nbj);

    __syncthreads();  // buf[cur] staging complete (vmcnt drain at barrier)

    bool have_prev = (k > 0);
    if (have_prev) load_scalars(pbi, pbj);  // L2-hit loads, consumed in epi

    if (have_next) stage(nbi, nbj, cur ^ 1);  // async prefetch, other buffer

    // MFMA(cur tile) interleaved (separate pipes) with epilogue(prev tile)
    if (k & 1) {
      domfma(accB);
      if (have_prev) epi(accA);
    } else {
      domfma(accA);
      if (have_prev) epi(accB);
    }

    pbi = bi; pbj = bj;
    tile = ntile; bi = nbi; bj = nbj; cur ^= 1; ++k;
  }

  // drain: epilogue for the last computed tile (bank = parity of k-1)
  load_scalars(pbi, pbj);
  if ((k - 1) & 1) epi(accB);
  else             epi(accA);

  // ---- once per block: reduce 16 waves, 1 scaled atomic into out[0] ----
#pragma unroll
  for (int off = 32; off; off >>= 1) stt += __shfl_down(stt, off);
  if (lane == 0) red[w] = stt;
  __syncthreads();
  if (t == 0) {
    float a = 0.f;
#pragma unroll
    for (int q = 0; q < 16; q++) a += red[q];
    atomicAdd(&out[0], a * (10.0f / ((float)NROWS * (float)NROWS)));
  }
}

extern "C" void kernel_launch(void* const* d_in, const int* in_sizes, int n_in,
                              void* d_out, int out_size, void* d_ws,
                              size_t ws_size, hipStream_t stream) {
  // inputs: 0=merged (unused), 1=input1 (unused), 2=samples, 3=labels
  const float* samples = (const float*)d_in[2];
  const int*   labels  = (const int*)d_in[3];

  char* ws = (char*)d_ws;
  unsigned char* sf8 = (unsigned char*)ws;                  // 2 MiB fp8
  float2* meta = (float2*)(ws + (size_t)NROWS * KDIM);      // 64 KiB
  float* out   = (float*)d_out;

  prep_kernel<<<GRID, 256, 0, stream>>>(samples, labels, sf8, meta, out);
  pair_kernel<<<GRID, 1024, 0, stream>>>(sf8, meta, out);
}

// Round 8
// 129.125 us; speedup vs baseline: 1.7768x; 1.7579x over previous
//
#include <hip/hip_runtime.h>

#define NROWS 8192
#define KDIM  256
#define NT    64                  // NROWS / 128
#define NBLK  (NT * (NT + 1) / 2) // 2080 upper-triangular 128x128 tiles
#define GRID  512                 // pair blocks; 2 per CU (single-buffer LDS)

typedef __attribute__((ext_vector_type(4)))  float f32x4;
typedef __attribute__((ext_vector_type(16))) float f32x16;
typedef __attribute__((ext_vector_type(4)))  int   i32x4;
typedef __attribute__((ext_vector_type(8)))  int   i32x8;

// async global->LDS, 16B per lane; LDS dest is wave-uniform base + lane*16
#define GLD(gp, lp)                                                            \
  __builtin_amdgcn_global_load_lds(                                            \
      (const __attribute__((address_space(1))) void*)(gp),                     \
      (__attribute__((address_space(3))) void*)(lp), 16, 0, 0)

// ---------------------------------------------------------------------------
// Kernel 1: fp32 -> fp8 e4m3 (OCP) convert + per-row meta {sumsq/256, label}.
// 256 blocks x 256 threads, one wave per row (grid-stride, 8 rows/wave).
// Also zeroes out[0] (pair_kernel atomics accumulate the final scalar there).
// ---------------------------------------------------------------------------
__global__ __launch_bounds__(256) void prep_kernel(
    const float* __restrict__ samples, const int* __restrict__ labels,
    unsigned char* __restrict__ sf8, float2* __restrict__ meta,
    float* __restrict__ out) {
  int tid = blockIdx.x * 256 + threadIdx.x;
  int gw = tid >> 6;        // global wave id, 0..1023
  int lane = tid & 63;
#pragma unroll
  for (int it = 0; it < NROWS / 1024; ++it) {
    int row = gw + it * 1024;
    f32x4 v = ((const f32x4*)samples)[(size_t)row * 64 + lane];
    int pk = __builtin_amdgcn_cvt_pk_fp8_f32(v.x, v.y, 0, false);
    pk = __builtin_amdgcn_cvt_pk_fp8_f32(v.z, v.w, pk, true);
    ((unsigned int*)sf8)[(size_t)row * 64 + lane] = (unsigned int)pk;
    float p = v.x * v.x + v.y * v.y + v.z * v.z + v.w * v.w;
#pragma unroll
    for (int off = 32; off; off >>= 1) p += __shfl_down(p, off);
    if (lane == 0)
      meta[row] = make_float2(p * (1.0f / 256.0f), (float)labels[row]);
  }
  if (tid == 0) out[0] = 0.0f;
}

// decode triangular index b -> (bi, bj), bi <= bj  (verified over 0..NBLK-1)
__device__ inline void decode_tile(int b, int& bi, int& bj) {
  float disc = (2.0f * NT + 1.0f) * (2.0f * NT + 1.0f) - 8.0f * (float)b;
  bi = (int)(((2.0f * NT + 1.0f) - sqrtf(disc)) * 0.5f);
  if (bi < 0) bi = 0;
  if (bi > NT - 1) bi = NT - 1;
  while (bi > 0 && (bi * NT - bi * (bi - 1) / 2) > b) --bi;
  while (((bi + 1) * NT - (bi + 1) * bi / 2) <= b) ++bi;
  bj = bi + (b - (bi * NT - bi * (bi - 1) / 2));
}

// ---------------------------------------------------------------------------
// Kernel 2: 512 persistent blocks of 512 threads, TWO BLOCKS PER CU.
//
// Occupancy history: R5 (1 block/CU, 2 waves/SIMD) was latency-bound
// (MfmaUtil 6.4%, ~8.5k stall cy/tile). R6/R7 (1024-thr blocks) hit the
// compiler's 64-VGPR cap for 1024-thr workgroups -> 429 MB scratch spill.
// Empirically __launch_bounds__'s 2nd arg behaves as min BLOCKS per CU
// (CUDA semantics): (512,1)->128 regs, (1024,*)->64 regs.
// => 512-thr blocks, __launch_bounds__(512,2): cap = 2048/16 waves = 128,
// working set ~90 regs (no spill), 2 blocks/CU = 4 waves/SIMD.
//
// SINGLE-buffered 128x128 fp8 tile (64 KB LDS -> two blocks fit in 160 KB).
// The co-resident block replaces both the double buffer and the deferred
// epilogue: its MFMA phase covers this block's stage/barrier stall (m114:
// MFMA/VALU/VMEM pipes co-schedule fully across waves).
// STRIDED tile walk (tile += GRID): all blocks work one contiguous band ->
// each A panel shared by many blocks in L2 (R4 proved chunked walks break
// this). XOR-16B swizzle on the GLOBAL side of global_load_lds; fragment
// reads apply the involution on the LDS side. 8 waves, each a 32x64
// quadrant = 2 chains of 4 dependent mfma_scale 32x32x64 fp8 (e8m0 scale
// 127 = 1.0 -> plain fp8 numerics at 2.3x the non-scaled rate).
// One scaled atomic into out[0] per block.
// ---------------------------------------------------------------------------
__global__ __launch_bounds__(512, 2) void pair_kernel(
    const unsigned char* __restrict__ sf8, const float2* __restrict__ meta,
    float* __restrict__ out) {

  __shared__ __align__(16) unsigned char As[128 * 256];
  __shared__ __align__(16) unsigned char Bs[128 * 256];
  __shared__ float red[8];

  int t = threadIdx.x;
  int lane = t & 63;
  int w = t >> 6;               // 0..7
  int wm = w >> 1, wn = w & 1;  // wave quadrant: rows wm*32+, cols wn*64+
  int lr = lane >> 4, pc = lane & 15;  // staging: row-in-region, phys chunk
  int l31 = lane & 31;                 // fragment row/col within 32
  int hk  = lane >> 5;                 // k-half selector (0/1)

  float stt = 0.f;

  // stage tile (bi,bj): 32 regions x 1KB per matrix, wave w owns regions
  // {w, 8+w, 16+w, 24+w}; XOR-16B swizzle applied on the GLOBAL side
  auto stage = [&](int bi_, int bj_) {
    int rA = bi_ * 128, rB = bj_ * 128;
#pragma unroll
    for (int p = 0; p < 4; ++p) {
      int region = p * 8 + w;
      int rr = region * 4 + lr;
      int c = pc ^ (rr & 15);
      GLD(sf8 + (size_t)(rA + rr) * KDIM + c * 16, &As[region * 1024]);
      GLD(sf8 + (size_t)(rB + rr) * KDIM + c * 16, &Bs[region * 1024]);
    }
  };

  int tile = blockIdx.x;
  int bi, bj;

  while (tile < NBLK) {
    decode_tile(tile, bi, bj);

    // issue async staging first; scalar loads queue behind them (in-order
    // vmcnt), their waits before epi use are satisfied post-barrier anyway
    stage(bi, bj);

    // per-row scalars for THIS tile (L2-hit); latency hides under the stage
    // C/D layout (32x32): col = lane&31, row = (reg&3)+8*(reg>>2)+4*(lane>>5)
    float sqa[16], laa[16], sqb[2], labv[2];
#pragma unroll
    for (int g = 0; g < 4; ++g) {
      int gr = bi * 128 + wm * 32 + g * 8 + 4 * hk;  // rows gr..gr+3
      f32x4 m0 = *(const f32x4*)(meta + gr);
      f32x4 m1 = *(const f32x4*)(meta + gr + 2);
      sqa[g * 4 + 0] = m0.x; laa[g * 4 + 0] = m0.y;
      sqa[g * 4 + 1] = m0.z; laa[g * 4 + 1] = m0.w;
      sqa[g * 4 + 2] = m1.x; laa[g * 4 + 2] = m1.y;
      sqa[g * 4 + 3] = m1.z; laa[g * 4 + 3] = m1.w;
    }
#pragma unroll
    for (int j = 0; j < 2; ++j) {
      float2 mb = meta[bj * 128 + wn * 64 + j * 32 + l31];
      sqb[j] = mb.x; labv[j] = mb.y;
    }
    float wt = (bi == bj) ? 1.0f : 2.0f;

    __syncthreads();  // staging complete (vmcnt drained at barrier)

    // ---- MFMA phase: 8x mfma_scale 32x32x64 fp8 (e8m0 127 = 1.0) ----
    f32x16 acc[2];
#pragma unroll
    for (int j = 0; j < 2; ++j)
#pragma unroll
      for (int e = 0; e < 16; ++e) acc[j][e] = 0.f;

    int m = wm * 32 + l31;
    const unsigned char* ab = &As[m * 256];
    int sm = m & 15;
#pragma unroll
    for (int kt = 0; kt < 4; ++kt) {
      int c0 = kt * 4 + hk * 2;  // logical 16B-chunk pair for this lane
      i32x4 alo = *(const i32x4*)(ab + ((c0 ^ sm) << 4));
      i32x4 ahi = *(const i32x4*)(ab + (((c0 + 1) ^ sm) << 4));
      i32x8 av = {alo.x, alo.y, alo.z, alo.w, ahi.x, ahi.y, ahi.z, ahi.w};
#pragma unroll
      for (int j = 0; j < 2; ++j) {
        int n = wn * 64 + j * 32 + l31;
        const unsigned char* bb = &Bs[n * 256];
        int sn = n & 15;
        i32x4 blo = *(const i32x4*)(bb + ((c0 ^ sn) << 4));
        i32x4 bhi = *(const i32x4*)(bb + (((c0 + 1) ^ sn) << 4));
        i32x8 bv = {blo.x, blo.y, blo.z, blo.w, bhi.x, bhi.y, bhi.z, bhi.w};
        acc[j] = __builtin_amdgcn_mfma_scale_f32_32x32x64_f8f6f4(
            av, bv, acc[j], 0, 0, 0, 127, 0, 127);
      }
    }

    // ---- epilogue: gram -> S -> hinge/same, single accumulator ----
    float s = 0.f;
#pragma unroll
    for (int j = 0; j < 2; ++j) {
#pragma unroll
      for (int g2 = 0; g2 < 16; ++g2) {
        float S = sqa[g2] + sqb[j] - acc[j][g2] * (1.0f / 128.0f);
        float h = fmaxf(0.f, 1.f - S);
        s += (laa[g2] == labv[j]) ? S : h;
      }
    }
    stt += wt * s;

    tile += GRID;
    if (tile < NBLK) __syncthreads();  // LDS reads done before next stage
  }

  // ---- once per block: reduce 8 waves, 1 scaled atomic into out[0] ----
#pragma unroll
  for (int off = 32; off; off >>= 1) stt += __shfl_down(stt, off);
  if (lane == 0) red[w] = stt;
  __syncthreads();
  if (t == 0) {
    float a = 0.f;
#pragma unroll
    for (int q = 0; q < 8; q++) a += red[q];
    atomicAdd(&out[0], a * (10.0f / ((float)NROWS * (float)NROWS)));
  }
}

extern "C" void kernel_launch(void* const* d_in, const int* in_sizes, int n_in,
                              void* d_out, int out_size, void* d_ws,
                              size_t ws_size, hipStream_t stream) {
  // inputs: 0=merged (unused), 1=input1 (unused), 2=samples, 3=labels
  const float* samples = (const float*)d_in[2];
  const int*   labels  = (const int*)d_in[3];

  char* ws = (char*)d_ws;
  unsigned char* sf8 = (unsigned char*)ws;                  // 2 MiB fp8
  float2* meta = (float2*)(ws + (size_t)NROWS * KDIM);      // 64 KiB
  float* out   = (float*)d_out;

  prep_kernel<<<256, 256, 0, stream>>>(samples, labels, sf8, meta, out);
  pair_kernel<<<GRID, 512, 0, stream>>>(sf8, meta, out);
}

// Round 9
// 128.546 us; speedup vs baseline: 1.7848x; 1.0045x over previous
//
#include <hip/hip_runtime.h>

#define NROWS 8192
#define KDIM  256
#define NT    64                  // NROWS / 128
#define NBLK  (NT * (NT + 1) / 2) // 2080 upper-triangular 128x128 tiles
#define GRID  512                 // pair blocks; 2 per CU

typedef __attribute__((ext_vector_type(4)))  float f32x4;
typedef __attribute__((ext_vector_type(16))) float f32x16;
typedef __attribute__((ext_vector_type(4)))  int   i32x4;
typedef __attribute__((ext_vector_type(8)))  int   i32x8;

// async global->LDS, 16B per lane; LDS dest is wave-uniform base + lane*16
#define GLD(gp, lp)                                                            \
  __builtin_amdgcn_global_load_lds(                                            \
      (const __attribute__((address_space(1))) void*)(gp),                     \
      (__attribute__((address_space(3))) void*)(lp), 16, 0, 0)

// ---------------------------------------------------------------------------
// Kernel 1: fp32 -> fp8 e4m3 (OCP) convert + per-row meta {sumsq/256, label}.
// 256 blocks x 256 threads, one wave per row (grid-stride, 8 rows/wave).
// Also zeroes out[0] (pair_kernel atomics accumulate the final scalar there).
// ---------------------------------------------------------------------------
__global__ __launch_bounds__(256) void prep_kernel(
    const float* __restrict__ samples, const int* __restrict__ labels,
    unsigned char* __restrict__ sf8, float2* __restrict__ meta,
    float* __restrict__ out) {
  int tid = blockIdx.x * 256 + threadIdx.x;
  int gw = tid >> 6;        // global wave id, 0..1023
  int lane = tid & 63;
#pragma unroll
  for (int it = 0; it < NROWS / 1024; ++it) {
    int row = gw + it * 1024;
    f32x4 v = ((const f32x4*)samples)[(size_t)row * 64 + lane];
    int pk = __builtin_amdgcn_cvt_pk_fp8_f32(v.x, v.y, 0, false);
    pk = __builtin_amdgcn_cvt_pk_fp8_f32(v.z, v.w, pk, true);
    ((unsigned int*)sf8)[(size_t)row * 64 + lane] = (unsigned int)pk;
    float p = v.x * v.x + v.y * v.y + v.z * v.z + v.w * v.w;
#pragma unroll
    for (int off = 32; off; off >>= 1) p += __shfl_down(p, off);
    if (lane == 0)
      meta[row] = make_float2(p * (1.0f / 256.0f), (float)labels[row]);
  }
  if (tid == 0) out[0] = 0.0f;
}

// decode triangular index b -> (bi, bj), bi <= bj  (verified over 0..NBLK-1)
__device__ inline void decode_tile(int b, int& bi, int& bj) {
  float disc = (2.0f * NT + 1.0f) * (2.0f * NT + 1.0f) - 8.0f * (float)b;
  bi = (int)(((2.0f * NT + 1.0f) - sqrtf(disc)) * 0.5f);
  if (bi < 0) bi = 0;
  if (bi > NT - 1) bi = NT - 1;
  while (bi > 0 && (bi * NT - bi * (bi - 1) / 2) > b) --bi;
  while (((bi + 1) * NT - (bi + 1) * bi / 2) <= b) ++bi;
  bj = bi + (b - (bi * NT - bi * (bi - 1) / 2));
}

// ---------------------------------------------------------------------------
// Kernel 2: K-CHUNKED DOUBLE BUFFER at 2 blocks/CU -- combines the two
// independently-proven wins that R8 showed cancel when separated:
//   * occupancy (R8): 512-thr blocks, __launch_bounds__(512,2) [2nd arg =
//     min BLOCKS/CU per R6-R8], 4 waves/SIMD, no spill (cap 128 VGPR).
//   * pipelining (R3): every stage flies behind a compute phase with one
//     barrier per chunk; K=256 split into two 128-deep chunks so the double
//     buffer fits 2 blocks/CU: LDS = 2 x (128x128 A + 128x128 B) = 65.5 KB.
// Chunk c of every tile lives in buf c. Hazards: SYNC_A = {chunk0 staged,
// prior tile's buf1 reads done}; SYNC_B = {chunk1 staged, buf0 reads done}.
// Rows are 128 B -> XOR swizzle chunk^=(row&7) (8 slots; residual 4-way
// conflict ~1.6x LDS pipe, acceptable). STRIDED tile walk (tile += GRID)
// keeps the contiguous-band L2 sharing R4 proved essential.
// 8 waves, each a 32x64 quadrant; acc accumulates across both chunks;
// mfma_scale 32x32x64 fp8 (e8m0 127 = 1.0 -> plain fp8 numerics).
// One scaled atomic into out[0] per block.
// ---------------------------------------------------------------------------
__global__ __launch_bounds__(512, 2) void pair_kernel(
    const unsigned char* __restrict__ sf8, const float2* __restrict__ meta,
    float* __restrict__ out) {

  __shared__ __align__(16) unsigned char As[2][128 * 128];
  __shared__ __align__(16) unsigned char Bs[2][128 * 128];
  __shared__ float red[8];

  int t = threadIdx.x;
  int lane = t & 63;
  int w = t >> 6;               // 0..7
  int wm = w >> 1, wn = w & 1;  // wave quadrant: rows wm*32+, cols wn*64+
  int lr = lane >> 3, pc = lane & 7;  // staging: row-in-region, 16B slot
  int l31 = lane & 31;                // fragment row/col within 32
  int hk  = lane >> 5;                // k-half selector (0/1)

  float stt = 0.f;

  // stage one 128-row x 128B K-chunk (ck=0/1) of a panel into buf `ck`.
  // 16 regions x 1KB (8 rows of 128B each); wave w owns regions {w, 8+w}.
  // XOR-16B swizzle on the GLOBAL side: slot pc holds chunk pc^(row&7).
  auto stageA = [&](int bi_, int ck) {
    int rA = bi_ * 128;
#pragma unroll
    for (int p = 0; p < 2; ++p) {
      int region = p * 8 + w;          // 0..15
      int rr = region * 8 + lr;        // row 0..127
      int c = pc ^ (rr & 7);
      GLD(sf8 + (size_t)(rA + rr) * KDIM + ck * 128 + c * 16,
          &As[ck][region * 1024]);
    }
  };
  auto stageB = [&](int bj_, int ck) {
    int rB = bj_ * 128;
#pragma unroll
    for (int p = 0; p < 2; ++p) {
      int region = p * 8 + w;
      int rr = region * 8 + lr;
      int c = pc ^ (rr & 7);
      GLD(sf8 + (size_t)(rB + rr) * KDIM + ck * 128 + c * 16,
          &Bs[ck][region * 1024]);
    }
  };

  // one K-chunk of MFMA: 2 kt x 2 j mfma_scale 32x32x64 fp8, accumulate
  auto domfma = [&](f32x16 (&acc)[2], int ck) {
    int m = wm * 32 + l31;
    const unsigned char* ab = &As[ck][m * 128];
    int sm = m & 7;
#pragma unroll
    for (int kt = 0; kt < 2; ++kt) {
      int c0 = kt * 4 + hk * 2;  // logical 16B-slot pair for this lane
      i32x4 alo = *(const i32x4*)(ab + ((c0 ^ sm) << 4));
      i32x4 ahi = *(const i32x4*)(ab + (((c0 + 1) ^ sm) << 4));
      i32x8 av = {alo.x, alo.y, alo.z, alo.w, ahi.x, ahi.y, ahi.z, ahi.w};
#pragma unroll
      for (int j = 0; j < 2; ++j) {
        int n = wn * 64 + j * 32 + l31;
        const unsigned char* bb = &Bs[ck][n * 128];
        int sn = n & 7;
        i32x4 blo = *(const i32x4*)(bb + ((c0 ^ sn) << 4));
        i32x4 bhi = *(const i32x4*)(bb + (((c0 + 1) ^ sn) << 4));
        i32x8 bv = {blo.x, blo.y, blo.z, blo.w, bhi.x, bhi.y, bhi.z, bhi.w};
        acc[j] = __builtin_amdgcn_mfma_scale_f32_32x32x64_f8f6f4(
            av, bv, acc[j], 0, 0, 0, 127, 0, 127);
      }
    }
  };

  int tile = blockIdx.x;
  int bi, bj;
  decode_tile(tile, bi, bj);
  stageA(bi, 0);
  stageB(bj, 0);

  while (tile < NBLK) {
    __syncthreads();  // SYNC_A: chunk0 staged; prior tile's buf1 reads done

    // per-row scalars for THIS tile (L2-hit); drain at SYNC_B, flight =
    // chunk1-stage issue + chunk0 MFMA phase.
    // C/D layout (32x32): col = lane&31, row = (reg&3)+8*(reg>>2)+4*(lane>>5)
    float sqa[16], laa[16], sqb[2], labv[2];
#pragma unroll
    for (int g = 0; g < 4; ++g) {
      int gr = bi * 128 + wm * 32 + g * 8 + 4 * hk;  // rows gr..gr+3
      f32x4 m0 = *(const f32x4*)(meta + gr);
      f32x4 m1 = *(const f32x4*)(meta + gr + 2);
      sqa[g * 4 + 0] = m0.x; laa[g * 4 + 0] = m0.y;
      sqa[g * 4 + 1] = m0.z; laa[g * 4 + 1] = m0.w;
      sqa[g * 4 + 2] = m1.x; laa[g * 4 + 2] = m1.y;
      sqa[g * 4 + 3] = m1.z; laa[g * 4 + 3] = m1.w;
    }
#pragma unroll
    for (int j = 0; j < 2; ++j) {
      float2 mb = meta[bj * 128 + wn * 64 + j * 32 + l31];
      sqb[j] = mb.x; labv[j] = mb.y;
    }
    float wt = (bi == bj) ? 1.0f : 2.0f;

    stageA(bi, 1);  // prefetch chunk1 behind chunk0's MFMA
    stageB(bj, 1);

    f32x16 acc[2];
#pragma unroll
    for (int j = 0; j < 2; ++j)
#pragma unroll
      for (int e = 0; e < 16; ++e) acc[j][e] = 0.f;

    domfma(acc, 0);

    __syncthreads();  // SYNC_B: chunk1 staged; all buf0 reads done

    int ntile = tile + GRID;
    int nbi = 0, nbj = 0;
    bool have_next = ntile < NBLK;
    if (have_next) {
      decode_tile(ntile, nbi, nbj);
      stageA(nbi, 0);  // prefetch next tile's chunk0 behind chunk1's MFMA
      stageB(nbj, 0);
    }

    domfma(acc, 1);

    // ---- epilogue: gram -> S -> hinge/same, single accumulator ----
    float s = 0.f;
#pragma unroll
    for (int j = 0; j < 2; ++j) {
#pragma unroll
      for (int g2 = 0; g2 < 16; ++g2) {
        float S = sqa[g2] + sqb[j] - acc[j][g2] * (1.0f / 128.0f);
        float h = fmaxf(0.f, 1.f - S);
        s += (laa[g2] == labv[j]) ? S : h;
      }
    }
    stt += wt * s;

    tile = ntile; bi = nbi; bj = nbj;
  }

  // ---- once per block: reduce 8 waves, 1 scaled atomic into out[0] ----
#pragma unroll
  for (int off = 32; off; off >>= 1) stt += __shfl_down(stt, off);
  if (lane == 0) red[w] = stt;
  __syncthreads();
  if (t == 0) {
    float a = 0.f;
#pragma unroll
    for (int q = 0; q < 8; q++) a += red[q];
    atomicAdd(&out[0], a * (10.0f / ((float)NROWS * (float)NROWS)));
  }
}

extern "C" void kernel_launch(void* const* d_in, const int* in_sizes, int n_in,
                              void* d_out, int out_size, void* d_ws,
                              size_t ws_size, hipStream_t stream) {
  // inputs: 0=merged (unused), 1=input1 (unused), 2=samples, 3=labels
  const float* samples = (const float*)d_in[2];
  const int*   labels  = (const int*)d_in[3];

  char* ws = (char*)d_ws;
  unsigned char* sf8 = (unsigned char*)ws;                  // 2 MiB fp8
  float2* meta = (float2*)(ws + (size_t)NROWS * KDIM);      // 64 KiB
  float* out   = (float*)d_out;

  prep_kernel<<<256, 256, 0, stream>>>(samples, labels, sf8, meta, out);
  pair_kernel<<<GRID, 512, 0, stream>>>(sf8, meta, out);
}

// Round 10
// 123.719 us; speedup vs baseline: 1.8545x; 1.0390x over previous
//
#include <hip/hip_runtime.h>

#define NROWS 8192
#define KDIM  256
#define NT    64                  // NROWS / 128
#define NBLK  (NT * (NT + 1) / 2) // 2080 upper-triangular 128x128 tiles
#define GRID  256                 // persistent blocks; 8-9 tiles each

typedef __attribute__((ext_vector_type(4)))  float f32x4;
typedef __attribute__((ext_vector_type(16))) float f32x16;
typedef __attribute__((ext_vector_type(4)))  int   i32x4;
typedef __attribute__((ext_vector_type(8)))  int   i32x8;

// async global->LDS, 16B per lane; LDS dest is wave-uniform base + lane*16
#define GLD(gp, lp)                                                            \
  __builtin_amdgcn_global_load_lds(                                            \
      (const __attribute__((address_space(1))) void*)(gp),                     \
      (__attribute__((address_space(3))) void*)(lp), 16, 0, 0)

// ---------------------------------------------------------------------------
// Kernel 1: fp32 -> fp8 e4m3 (OCP) convert + per-row meta {sumsq/256, label}.
// Also zeroes out[0] (pair_kernel atomics accumulate the final scalar there).
// ---------------------------------------------------------------------------
__global__ void prep_kernel(const float* __restrict__ samples,
                            const int* __restrict__ labels,
                            unsigned char* __restrict__ sf8,
                            float2* __restrict__ meta,
                            float* __restrict__ out) {
  int row = blockIdx.x, t = threadIdx.x;  // t in [0,128)
  float2 v2 = ((const float2*)samples)[(size_t)row * 128 + t];
  int pk = __builtin_amdgcn_cvt_pk_fp8_f32(v2.x, v2.y, 0, false);
  ((unsigned short*)sf8)[(size_t)row * 128 + t] = (unsigned short)(pk & 0xffff);
  float p = v2.x * v2.x + v2.y * v2.y;
#pragma unroll
  for (int off = 32; off; off >>= 1) p += __shfl_down(p, off);
  __shared__ float ws2[2];
  if ((t & 63) == 0) ws2[t >> 6] = p;
  __syncthreads();
  if (t == 0) {
    float tot = ws2[0] + ws2[1];
    meta[row] = make_float2(tot * (1.0f / 256.0f), (float)labels[row]);
  }
  if (row == 0 && t == 0) out[0] = 0.0f;
}

// decode triangular index b -> (bi, bj), bi <= bj  (verified over 0..NBLK-1)
__device__ inline void decode_tile(int b, int& bi, int& bj) {
  float disc = (2.0f * NT + 1.0f) * (2.0f * NT + 1.0f) - 8.0f * (float)b;
  bi = (int)(((2.0f * NT + 1.0f) - sqrtf(disc)) * 0.5f);
  if (bi < 0) bi = 0;
  if (bi > NT - 1) bi = NT - 1;
  while (bi > 0 && (bi * NT - bi * (bi - 1) / 2) > b) --bi;
  while (((bi + 1) * NT - (bi + 1) * bi / 2) <= b) ++bi;
  bj = bi + (b - (bi * NT - bi * (bi - 1) / 2));
}

// ---------------------------------------------------------------------------
// Kernel 2: persistent blocks, tile-level double-buffered fp8 Gram tiles.
// 512 threads = 8 waves, each wave a 32x64 quadrant (1x2 grid of 32x32x64
// MX-scaled MFMA; scale = e8m0 127 = 1.0, numerically plain fp8).
// DEFERRED EPILOGUE (T15): two acc banks ping-pong; tile t's epilogue VALU
// interleaves with tile t+1's MFMA phase (separate pipes, MFMA chain-stall
// issue slots absorb it). Per tile: ONE barrier; 64KB prefetch flies behind
// MFMA. Loss accumulates in one register; one reduction + 1 scaled atomic
// directly into out[0] per block (finalize kernel eliminated).
//
// CHAMPION (R3, 122.4 us). Structural record from R4-R9 probes:
//  * strided walk (tile += GRID) is load-bearing: all blocks share one
//    contiguous 256-tile band -> A panels L2-shared ~32x (R4 chunked: -2.4)
//  * fusion w/ grid barrier: acquire fence invalidates L2 (R5: -14)
//  * 1024-thr blocks: compiler caps 64 VGPR -> 429 MB spill (R6/R7: -105)
//  * single-buffer or half-K dbuf @ 2 blocks/CU: lost prefetch flight
//    cancels the occupancy gain exactly (R8: -6.7, R9: -6.1)
// ---------------------------------------------------------------------------
__global__ __launch_bounds__(512, 1) void pair_kernel(
    const unsigned char* __restrict__ sf8, const float2* __restrict__ meta,
    float* __restrict__ out) {

  __shared__ __align__(16) unsigned char As[2][128 * 256];
  __shared__ __align__(16) unsigned char Bs[2][128 * 256];
  __shared__ float red[8];

  int t = threadIdx.x;
  int lane = t & 63;
  int w = t >> 6;               // 0..7
  int wm = w >> 1, wn = w & 1;  // wave quadrant: rows wm*32+, cols wn*64+
  int lr = lane >> 4, pc = lane & 15;  // staging: row-in-region, phys chunk
  int l31 = lane & 31;                 // fragment row/col within 32
  int hk  = lane >> 5;                 // k-half selector (0/1)

  float stt = 0.f;

  // stage tile (bi,bj): 32 regions x 1KB per matrix, XOR-16B swizzle applied
  // on the GLOBAL side (LDS dest stays wave-uniform base + lane*16)
  auto stage = [&](int bi_, int bj_, int buf) {
    int rA = bi_ * 128, rB = bj_ * 128;
#pragma unroll
    for (int p = 0; p < 4; ++p) {
      int region = p * 8 + w;
      int rr = region * 4 + lr;
      int c = pc ^ (rr & 15);
      GLD(sf8 + (size_t)(rA + rr) * KDIM + c * 16, &As[buf][region * 1024]);
      GLD(sf8 + (size_t)(rB + rr) * KDIM + c * 16, &Bs[buf][region * 1024]);
    }
  };

  int tile = blockIdx.x;
  int bi, bj;
  decode_tile(tile, bi, bj);
  stage(bi, bj, 0);
  int cur = 0;

  // deferred-epilogue state (scalars reloaded per iter; meta is L2-resident)
  int pbi = 0, pbj = 0;
  float sqa[16], laa[16], sqb[2], labv[2], pwt = 1.f;
  f32x16 accA[2], accB[2];

  // per-row scalars for the deferred tile; issued BEFORE prefetch GLDs so
  // their (in-order) vmcnt waits don't force prefetch completion.
  // C/D layout (32x32): col = lane&31, row = (reg&3)+8*(reg>>2)+4*(lane>>5)
  auto load_scalars = [&](int pbi_, int pbj_) {
#pragma unroll
    for (int g = 0; g < 4; ++g) {
      int gr = pbi_ * 128 + wm * 32 + g * 8 + 4 * hk;  // rows gr..gr+3
      f32x4 m0 = *(const f32x4*)(meta + gr);
      f32x4 m1 = *(const f32x4*)(meta + gr + 2);
      sqa[g * 4 + 0] = m0.x; laa[g * 4 + 0] = m0.y;
      sqa[g * 4 + 1] = m0.z; laa[g * 4 + 1] = m0.w;
      sqa[g * 4 + 2] = m1.x; laa[g * 4 + 2] = m1.y;
      sqa[g * 4 + 3] = m1.z; laa[g * 4 + 3] = m1.w;
    }
#pragma unroll
    for (int j = 0; j < 2; ++j) {
      float2 mb = meta[pbj_ * 128 + wn * 64 + j * 32 + l31];
      sqb[j] = mb.x; labv[j] = mb.y;
    }
    pwt = (pbi_ == pbj_) ? 1.0f : 2.0f;
  };

  // MFMA phase on buf[cur]: 8x mfma_scale 32x32x64 fp8 (e8m0 127 = 1.0)
  auto domfma = [&](f32x16 (&acc)[2]) {
#pragma unroll
    for (int j = 0; j < 2; ++j)
#pragma unroll
      for (int e = 0; e < 16; ++e) acc[j][e] = 0.f;
#pragma unroll
    for (int kt = 0; kt < 4; ++kt) {
      int c0 = kt * 4 + hk * 2;  // logical 16B-chunk pair for this lane
      int m = wm * 32 + l31;
      const unsigned char* ab = &As[cur][m * 256];
      int sm = m & 15;
      i32x4 alo = *(const i32x4*)(ab + ((c0 ^ sm) << 4));
      i32x4 ahi = *(const i32x4*)(ab + (((c0 + 1) ^ sm) << 4));
      i32x8 av = {alo.x, alo.y, alo.z, alo.w, ahi.x, ahi.y, ahi.z, ahi.w};
#pragma unroll
      for (int j = 0; j < 2; ++j) {
        int n = wn * 64 + j * 32 + l31;
        const unsigned char* bb = &Bs[cur][n * 256];
        int sn = n & 15;
        i32x4 blo = *(const i32x4*)(bb + ((c0 ^ sn) << 4));
        i32x4 bhi = *(const i32x4*)(bb + (((c0 + 1) ^ sn) << 4));
        i32x8 bv = {blo.x, blo.y, blo.z, blo.w, bhi.x, bhi.y, bhi.z, bhi.w};
        acc[j] = __builtin_amdgcn_mfma_scale_f32_32x32x64_f8f6f4(
            av, bv, acc[j], 0, 0, 0, 127, 0, 127);
      }
    }
  };

  // epilogue for the deferred tile: gram -> S -> hinge/same, one accumulator
  auto epi = [&](const f32x16 (&acc)[2]) {
    float s = 0.f;
#pragma unroll
    for (int j = 0; j < 2; ++j) {
#pragma unroll
      for (int g2 = 0; g2 < 16; ++g2) {
        float S = sqa[g2] + sqb[j] - acc[j][g2] * (1.0f / 128.0f);
        float h = fmaxf(0.f, 1.f - S);
        s += (laa[g2] == labv[j]) ? S : h;
      }
    }
    stt += pwt * s;
  };

  int k = 0;
  while (tile < NBLK) {
    int ntile = tile + GRID;
    int nbi = 0, nbj = 0;
    bool have_next = ntile < NBLK;
    if (have_next) decode_tile(ntile, nbi, nbj);

    __syncthreads();  // buf[cur] staging complete (vmcnt drain at barrier)

    bool have_prev = (k > 0);
    if (have_prev) load_scalars(pbi, pbj);  // L2-hit loads, consumed in epi

    if (have_next) stage(nbi, nbj, cur ^ 1);  // async prefetch, other buffer

    // MFMA(cur tile) interleaved (separate pipes) with epilogue(prev tile)
    if (k & 1) {
      domfma(accB);
      if (have_prev) epi(accA);
    } else {
      domfma(accA);
      if (have_prev) epi(accB);
    }

    pbi = bi; pbj = bj;
    tile = ntile; bi = nbi; bj = nbj; cur ^= 1; ++k;
  }

  // drain: epilogue for the last computed tile (bank = parity of k-1)
  load_scalars(pbi, pbj);
  if ((k - 1) & 1) epi(accB);
  else             epi(accA);

  // ---- once per block: reduce 8 waves, 1 scaled atomic into out[0] ----
#pragma unroll
  for (int off = 32; off; off >>= 1) stt += __shfl_down(stt, off);
  if (lane == 0) red[w] = stt;
  __syncthreads();
  if (t == 0) {
    float a = 0.f;
#pragma unroll
    for (int q = 0; q < 8; q++) a += red[q];
    atomicAdd(&out[0], a * (10.0f / ((float)NROWS * (float)NROWS)));
  }
}

extern "C" void kernel_launch(void* const* d_in, const int* in_sizes, int n_in,
                              void* d_out, int out_size, void* d_ws,
                              size_t ws_size, hipStream_t stream) {
  // inputs: 0=merged (unused), 1=input1 (unused), 2=samples, 3=labels
  const float* samples = (const float*)d_in[2];
  const int*   labels  = (const int*)d_in[3];

  char* ws = (char*)d_ws;
  unsigned char* sf8 = (unsigned char*)ws;                  // 2 MiB fp8
  float2* meta = (float2*)(ws + (size_t)NROWS * KDIM);      // 64 KiB
  float* out   = (float*)d_out;

  prep_kernel<<<NROWS, 128, 0, stream>>>(samples, labels, sf8, meta, out);
  pair_kernel<<<GRID, 512, 0, stream>>>(sf8, meta, out);
}